// Round 4
// baseline (1241.932 us; speedup 1.0000x reference)
//
#include <hip/hip_runtime.h>
#include <stdint.h>
#include <math.h>

typedef unsigned short u16;
typedef __attribute__((ext_vector_type(8))) __bf16 bf16x8;
typedef __attribute__((ext_vector_type(4))) float f32x4;
typedef __attribute__((ext_vector_type(4))) unsigned short u16x4;

__device__ __forceinline__ float b2f(u16 u) {
    unsigned int i = ((unsigned int)u) << 16;
    float f; __builtin_memcpy(&f, &i, 4); return f;
}
__device__ __forceinline__ u16 f2b(float f) {
    unsigned int i; __builtin_memcpy(&i, &f, 4);
    i = (i + 0x7FFFu + ((i >> 16) & 1u)) >> 16;   // RNE
    return (u16)i;
}
// load 8 consecutive fp32, convert to bf16x8 (RNE)
__device__ __forceinline__ bf16x8 ld8_cvt(const float* p) {
    float4 f0 = *(const float4*)p, f1 = *(const float4*)(p + 4);
    u16 t[8] = {f2b(f0.x), f2b(f0.y), f2b(f0.z), f2b(f0.w),
                f2b(f1.x), f2b(f1.y), f2b(f1.z), f2b(f1.w)};
    bf16x8 r; __builtin_memcpy(&r, t, 16); return r;
}

// ---------------------------------------------------------------------------
// Transpose + fp32->bf16 convert: in[R][C] fp32 -> out[C][R] bf16.
// block (32,8), grid (C/32, R/32)
// ---------------------------------------------------------------------------
__global__ __launch_bounds__(256) void transpose_f32_bf16(
    const float* __restrict__ in, u16* __restrict__ out, int R, int C)
{
    __shared__ float t[32][33];
    int bx = blockIdx.x * 32, by = blockIdx.y * 32;
    int x = threadIdx.x, y = threadIdx.y;
    #pragma unroll
    for (int j = 0; j < 32; j += 8)
        t[y + j][x] = in[(size_t)(by + y + j) * C + bx + x];
    __syncthreads();
    #pragma unroll
    for (int j = 0; j < 32; j += 8)
        out[(size_t)(bx + y + j) * R + by + x] = f2b(t[x][y + j]);
}

// ---------------------------------------------------------------------------
// GEMM: C[M,N] = A[M,K] @ Bt[N,K]^T (+bias, epilogue).  A fp32 or bf16
// (AF32 converts to bf16 at staging); Bt always bf16; acc fp32.
// EPI 0: C = acc + bias (bf16 out)   EPI 1: C = gelu_erf(acc + bias) (bf16 out)
// EPI 2: QKV permuted store into q/k/v [8,16,512,64] bf16 with per-matrix bias
// 128x128 tile, BK=32, 256 threads (4 waves, each 64x64 via 4x4 mfma 16x16x32)
// Staging: registers -> ds_write_b128 (m92/m93-verified), next-slab prefetch.
// ---------------------------------------------------------------------------
template<int EPI, bool AF32>
__global__ __launch_bounds__(256) void gemm_bt(
    const void* __restrict__ Av, const u16* __restrict__ Bt, int N, int K,
    u16* __restrict__ C, const float* __restrict__ bias,
    u16* __restrict__ qo, u16* __restrict__ ko, u16* __restrict__ vo,
    const float* __restrict__ bq, const float* __restrict__ bk,
    const float* __restrict__ bv)
{
    __shared__ __align__(16) u16 Asm[128 * 32];
    __shared__ __align__(16) u16 Bsm[128 * 32];
    const int tid  = threadIdx.x;
    const int lane = tid & 63, wave = tid >> 6;
    const int lrow = lane & 15, quad = lane >> 4;
    const int bm = blockIdx.x * 128, bn = blockIdx.y * 128;

    // staging slots: slot s in [0,512): row = s>>2, kcol = (s&3)*8.
    // thread t owns s = t and s = t+256 (row + 64). LDS elem offset = s*8.
    const int srow = tid >> 2;
    const int skol = (tid & 3) * 8;
    const float* gAf0 = (const float*)Av + (size_t)(bm + srow) * K + skol;
    const float* gAf1 = gAf0 + (size_t)64 * K;
    const u16*   gAh0 = (const u16*)Av + (size_t)(bm + srow) * K + skol;
    const u16*   gAh1 = gAh0 + (size_t)64 * K;
    const u16*   gB0  = Bt + (size_t)(bn + srow) * K + skol;
    const u16*   gB1  = gB0 + (size_t)64 * K;

    bf16x8 ra0, ra1, rb0, rb1;
    if (AF32) { ra0 = ld8_cvt(gAf0); ra1 = ld8_cvt(gAf1); }
    else      { ra0 = *(const bf16x8*)gAh0; ra1 = *(const bf16x8*)gAh1; }
    rb0 = *(const bf16x8*)gB0;
    rb1 = *(const bf16x8*)gB1;

    const int wm = wave >> 1, wn = wave & 1;
    f32x4 acc[4][4] = {};

    for (int kt = 0; kt < K; kt += 32) {
        __syncthreads();   // previous iteration's LDS reads complete
        *(bf16x8*)&Asm[(size_t)tid * 8]         = ra0;
        *(bf16x8*)&Asm[((size_t)tid + 256) * 8] = ra1;
        *(bf16x8*)&Bsm[(size_t)tid * 8]         = rb0;
        *(bf16x8*)&Bsm[((size_t)tid + 256) * 8] = rb1;
        __syncthreads();   // tiles visible to all waves

        if (kt + 32 < K) {   // uniform branch: prefetch next K-slab
            if (AF32) { ra0 = ld8_cvt(gAf0 + kt + 32); ra1 = ld8_cvt(gAf1 + kt + 32); }
            else      { ra0 = *(const bf16x8*)(gAh0 + kt + 32);
                        ra1 = *(const bf16x8*)(gAh1 + kt + 32); }
            rb0 = *(const bf16x8*)(gB0 + kt + 32);
            rb1 = *(const bf16x8*)(gB1 + kt + 32);
        }

        bf16x8 af[4], bf[4];
        #pragma unroll
        for (int mt = 0; mt < 4; mt++)
            af[mt] = *(const bf16x8*)&Asm[(wm * 64 + mt * 16 + lrow) * 32 + quad * 8];
        #pragma unroll
        for (int nt = 0; nt < 4; nt++)
            bf[nt] = *(const bf16x8*)&Bsm[(wn * 64 + nt * 16 + lrow) * 32 + quad * 8];
        #pragma unroll
        for (int mt = 0; mt < 4; mt++)
            #pragma unroll
            for (int nt = 0; nt < 4; nt++)
                acc[mt][nt] = __builtin_amdgcn_mfma_f32_16x16x32_bf16(
                    af[mt], bf[nt], acc[mt][nt], 0, 0, 0);
    }

    // epilogue: C/D layout col = lane&15, row = quad*4 + reg
    #pragma unroll
    for (int nt = 0; nt < 4; nt++) {
        int col = bn + wn * 64 + nt * 16 + lrow;
        int mat = 0, hh = 0, dd = 0;
        float bval;
        if (EPI == 2) {
            mat  = col >> 10; int dcol = col & 1023;
            hh = dcol >> 6;   dd = dcol & 63;
            const float* bp = (mat == 0) ? bq : ((mat == 1) ? bk : bv);
            bval = bp[dcol];
        } else {
            bval = bias[col];
        }
        #pragma unroll
        for (int mt = 0; mt < 4; mt++) {
            #pragma unroll
            for (int r = 0; r < 4; r++) {
                int row = bm + wm * 64 + mt * 16 + quad * 4 + r;
                float v = acc[mt][nt][r] + bval;
                if (EPI == 1) v = 0.5f * v * (1.0f + erff(v * 0.70710678118654752f));
                if (EPI == 2) {
                    int b = row >> 9, s = row & 511;   // b = batch within group (0..7)
                    u16* dst = (mat == 0) ? qo : ((mat == 1) ? ko : vo);
                    dst[(((size_t)(b * 16 + hh)) * 512 + s) * 64 + dd] = f2b(v);
                } else {
                    C[(size_t)row * N + col] = f2b(v);
                }
            }
        }
    }
}

// ---------------------------------------------------------------------------
// Flash attention: block = (qtile of 64, head, batch-in-group), 256 threads.
// q,k,v bf16 [8,16,512,64]; scores = q@k^T/8 + mask*-1e9 + adj(fp32);
// softmax; @v. ctx bf16 [4096,1024] (row = b_local*512 + qrow) for Wo GEMM.
// ---------------------------------------------------------------------------
__global__ __launch_bounds__(256) void attn_kernel(
    const u16* __restrict__ Q, const u16* __restrict__ Kb, const u16* __restrict__ Vb,
    const float* __restrict__ adj, const int* __restrict__ mask, u16* __restrict__ ctx)
{
    const int S = 512, H = 16;
    __shared__ __align__(16) u16 Ksm[32 * 64];      // [key][d]
    __shared__ __align__(16) u16 Vt [64 * 32];      // [d][key]
    __shared__ __align__(16) u16 Psm[4][16 * 32];   // per-wave P relayout buffer

    int tid = threadIdx.x, lane = tid & 63, wave = tid >> 6;
    int lrow = lane & 15, quad = lane >> 4;
    int qt = blockIdx.x, h = blockIdx.y, b = blockIdx.z;   // b = batch within group

    size_t headoff = ((size_t)(b * H + h)) * S * 64;
    const u16* qp = Q + headoff;
    const u16* kp = Kb + headoff;
    const u16* vp = Vb + headoff;
    const float* adjb = adj + (size_t)b * S * S;
    const int* maskb = mask + b * S;
    int q0 = qt * 64 + wave * 16;

    bf16x8 qf0 = *(const bf16x8*)(qp + (size_t)(q0 + lrow) * 64 + quad * 8);
    bf16x8 qf1 = *(const bf16x8*)(qp + (size_t)(q0 + lrow) * 64 + 32 + quad * 8);

    float m_run[4] = {-1e30f, -1e30f, -1e30f, -1e30f};
    float l_run[4] = {0.f, 0.f, 0.f, 0.f};
    f32x4 o[4] = {};

    int str = tid >> 3;          // 0..31  staging row (key)
    int stc = (tid & 7) * 8;     // 0..56  staging col (d)

    for (int kt = 0; kt < S; kt += 32) {
        __syncthreads();
        *(bf16x8*)&Ksm[str * 64 + stc] = *(const bf16x8*)(kp + (size_t)(kt + str) * 64 + stc);
        {
            bf16x8 vv = *(const bf16x8*)(vp + (size_t)(kt + str) * 64 + stc);
            const u16* tv = (const u16*)&vv;
            #pragma unroll
            for (int j = 0; j < 8; j++) Vt[(stc + j) * 32 + str] = tv[j];
        }
        __syncthreads();

        f32x4 sc[2];
        #pragma unroll
        for (int f = 0; f < 2; f++) {
            f32x4 cf = {};
            bf16x8 kf0 = *(const bf16x8*)&Ksm[(f * 16 + lrow) * 64 + quad * 8];
            bf16x8 kf1 = *(const bf16x8*)&Ksm[(f * 16 + lrow) * 64 + 32 + quad * 8];
            cf = __builtin_amdgcn_mfma_f32_16x16x32_bf16(qf0, kf0, cf, 0, 0, 0);
            cf = __builtin_amdgcn_mfma_f32_16x16x32_bf16(qf1, kf1, cf, 0, 0, 0);
            int key = kt + f * 16 + lrow;
            float mterm = maskb[key] ? -1e9f : 0.0f;
            #pragma unroll
            for (int r = 0; r < 4; r++) {
                int qrow = q0 + quad * 4 + r;
                sc[f][r] = cf[r] * 0.125f + mterm + adjb[(size_t)qrow * S + key];
            }
        }

        float mx[4], al[4], sm[4];
        #pragma unroll
        for (int r = 0; r < 4; r++) mx[r] = fmaxf(sc[0][r], sc[1][r]);
        #pragma unroll
        for (int mk = 1; mk < 16; mk <<= 1)
            #pragma unroll
            for (int r = 0; r < 4; r++) mx[r] = fmaxf(mx[r], __shfl_xor(mx[r], mk));
        #pragma unroll
        for (int r = 0; r < 4; r++) {
            float mn = fmaxf(m_run[r], mx[r]);
            al[r] = __expf(fminf(m_run[r] - mn, 0.f));
            m_run[r] = mn;
        }
        #pragma unroll
        for (int f = 0; f < 2; f++)
            #pragma unroll
            for (int r = 0; r < 4; r++)
                sc[f][r] = __expf(fminf(sc[f][r] - m_run[r], 0.f));
        #pragma unroll
        for (int r = 0; r < 4; r++) sm[r] = sc[0][r] + sc[1][r];
        #pragma unroll
        for (int mk = 1; mk < 16; mk <<= 1)
            #pragma unroll
            for (int r = 0; r < 4; r++) sm[r] += __shfl_xor(sm[r], mk);
        #pragma unroll
        for (int r = 0; r < 4; r++) l_run[r] = l_run[r] * al[r] + sm[r];
        #pragma unroll
        for (int nt = 0; nt < 4; nt++)
            #pragma unroll
            for (int r = 0; r < 4; r++) o[nt][r] *= al[r];

        #pragma unroll
        for (int f = 0; f < 2; f++)
            #pragma unroll
            for (int r = 0; r < 4; r++)
                Psm[wave][(quad * 4 + r) * 32 + f * 16 + lrow] = f2b(sc[f][r]);
        bf16x8 pa = *(const bf16x8*)&Psm[wave][lrow * 32 + quad * 8];
        #pragma unroll
        for (int nt = 0; nt < 4; nt++) {
            bf16x8 vf = *(const bf16x8*)&Vt[(nt * 16 + lrow) * 32 + quad * 8];
            o[nt] = __builtin_amdgcn_mfma_f32_16x16x32_bf16(pa, vf, o[nt], 0, 0, 0);
        }
    }

    // ctx[b_local*512 + qrow, h*64 + d]
    #pragma unroll
    for (int nt = 0; nt < 4; nt++)
        #pragma unroll
        for (int r = 0; r < 4; r++) {
            int qrow = q0 + quad * 4 + r;
            ctx[((size_t)b * 512 + qrow) * 1024 + h * 64 + nt * 16 + lrow] =
                f2b(o[nt][r] / l_run[r]);
        }
}

// ---------------------------------------------------------------------------
// out = LayerNorm(X + Y): mean over D=1024, unbiased std (ddof=1), /(std+1e-6)
// MODE 0: X fp32, Y bf16, out bf16   MODE 1: X bf16, Y bf16, out fp32
// ---------------------------------------------------------------------------
template<int MODE>
__global__ __launch_bounds__(256) void add_ln(
    const void* __restrict__ Xv, const void* __restrict__ Yv,
    const float* __restrict__ gamma, const float* __restrict__ beta,
    void* __restrict__ outv)
{
    const int D = 1024;
    int row = blockIdx.x, tid = threadIdx.x;
    int lane = tid & 63, wave = tid >> 6;
    size_t base = (size_t)row * D + tid * 4;

    float x[4];
    if (MODE == 0) {
        float4 xf = *(const float4*)((const float*)Xv + base);
        u16x4  uy = *(const u16x4*)((const u16*)Yv + base);
        x[0] = xf.x + b2f(uy[0]); x[1] = xf.y + b2f(uy[1]);
        x[2] = xf.z + b2f(uy[2]); x[3] = xf.w + b2f(uy[3]);
    } else {
        u16x4 ux = *(const u16x4*)((const u16*)Xv + base);
        u16x4 uy = *(const u16x4*)((const u16*)Yv + base);
        #pragma unroll
        for (int j = 0; j < 4; j++) x[j] = b2f(ux[j]) + b2f(uy[j]);
    }

    float s = x[0] + x[1] + x[2] + x[3];
    #pragma unroll
    for (int mk = 1; mk < 64; mk <<= 1) s += __shfl_xor(s, mk);
    __shared__ float red[8];
    if (lane == 0) red[wave] = s;
    __syncthreads();
    float mean = (red[0] + red[1] + red[2] + red[3]) * (1.0f / 1024.0f);

    float c[4], q = 0.f;
    #pragma unroll
    for (int j = 0; j < 4; j++) { c[j] = x[j] - mean; q += c[j] * c[j]; }
    #pragma unroll
    for (int mk = 1; mk < 64; mk <<= 1) q += __shfl_xor(q, mk);
    if (lane == 0) red[4 + wave] = q;
    __syncthreads();
    float var = (red[4] + red[5] + red[6] + red[7]) * (1.0f / 1023.0f);
    float inv = 1.0f / (sqrtf(var) + 1e-6f);

    float4 g4 = *(const float4*)(gamma + tid * 4);
    float4 b4 = *(const float4*)(beta + tid * 4);
    float gv[4] = {g4.x, g4.y, g4.z, g4.w};
    float bv[4] = {b4.x, b4.y, b4.z, b4.w};
    if (MODE == 0) {
        u16x4 ov;
        #pragma unroll
        for (int j = 0; j < 4; j++) ov[j] = f2b(gv[j] * c[j] * inv + bv[j]);
        *(u16x4*)((u16*)outv + base) = ov;
    } else {
        float4 ov;
        ov.x = gv[0] * c[0] * inv + bv[0];
        ov.y = gv[1] * c[1] * inv + bv[1];
        ov.z = gv[2] * c[2] * inv + bv[2];
        ov.w = gv[3] * c[3] * inv + bv[3];
        *(float4*)((float*)outv + base) = ov;
    }
}

// ---------------------------------------------------------------------------
// Workspace (bf16 unless noted), 96 MB peak:
//   [ 0, 6) Wqkv_t  [ 6, 8) Wo_t  [ 8,16) W1_t  [16,24) W2_t
//   [24,56) out1 (16384x1024)
//   attn phase (per 8-batch group): [56,64) q [64,72) k [72,80) v
//                                   [80,88) ctx [88,96) attn_out
//   FFN phase (per 4096-row chunk): [56,88) hidden [88,96) ffn
// ---------------------------------------------------------------------------
extern "C" void kernel_launch(void* const* d_in, const int* in_sizes, int n_in,
                              void* d_out, int out_size, void* d_ws, size_t ws_size,
                              hipStream_t stream)
{
    const float* x    = (const float*)d_in[0];
    const int*   mask = (const int*)d_in[1];
    const float* adj  = (const float*)d_in[2];
    const float* Wq = (const float*)d_in[4];  const float* bq = (const float*)d_in[5];
    const float* Wk = (const float*)d_in[6];  const float* bk = (const float*)d_in[7];
    const float* Wv = (const float*)d_in[8];  const float* bv = (const float*)d_in[9];
    const float* Wo = (const float*)d_in[10]; const float* bo = (const float*)d_in[11];
    const float* W1 = (const float*)d_in[12]; const float* b1 = (const float*)d_in[13];
    const float* W2 = (const float*)d_in[14]; const float* b2 = (const float*)d_in[15];
    const float* gamma = (const float*)d_in[16];
    const float* beta  = (const float*)d_in[17];
    float* out = (float*)d_out;

    const size_t MB = 1024ull * 1024;
    char* w = (char*)d_ws;
    u16* Wqkv_t = (u16*)(w + 0 * MB);
    u16* Wo_t   = (u16*)(w + 6 * MB);
    u16* W1_t   = (u16*)(w + 8 * MB);
    u16* W2_t   = (u16*)(w + 16 * MB);
    u16* out1   = (u16*)(w + 24 * MB);
    u16* qg     = (u16*)(w + 56 * MB);
    u16* kg     = (u16*)(w + 64 * MB);
    u16* vg     = (u16*)(w + 72 * MB);
    u16* ctxg   = (u16*)(w + 80 * MB);
    u16* aog    = (u16*)(w + 88 * MB);
    u16* hid    = (u16*)(w + 56 * MB);   // overlays q/k/v/ctx (dead in FFN phase)
    u16* ffn    = (u16*)(w + 88 * MB);   // overlays attn_out

    dim3 tb(32, 8);
    transpose_f32_bf16<<<dim3(32, 32),  tb, 0, stream>>>(Wq, Wqkv_t,                1024, 1024);
    transpose_f32_bf16<<<dim3(32, 32),  tb, 0, stream>>>(Wk, Wqkv_t + 1024ull*1024, 1024, 1024);
    transpose_f32_bf16<<<dim3(32, 32),  tb, 0, stream>>>(Wv, Wqkv_t + 2048ull*1024, 1024, 1024);
    transpose_f32_bf16<<<dim3(32, 32),  tb, 0, stream>>>(Wo, Wo_t,                  1024, 1024);
    transpose_f32_bf16<<<dim3(128, 32), tb, 0, stream>>>(W1, W1_t,                  1024, 4096);
    transpose_f32_bf16<<<dim3(32, 128), tb, 0, stream>>>(W2, W2_t,                  4096, 1024);

    // ---- attention phase: 4 groups of 8 batches (4096 rows each) ----
    for (int g = 0; g < 4; g++) {
        const float* xg = x + (size_t)g * 4096 * 1024;
        gemm_bt<2, true><<<dim3(32, 24), 256, 0, stream>>>(xg, Wqkv_t, 3072, 1024,
            nullptr, nullptr, qg, kg, vg, bq, bk, bv);
        attn_kernel<<<dim3(8, 16, 8), 256, 0, stream>>>(qg, kg, vg,
            adj + (size_t)g * 8 * 512 * 512, mask + g * 8 * 512, ctxg);
        gemm_bt<0, false><<<dim3(32, 8), 256, 0, stream>>>(ctxg, Wo_t, 1024, 1024,
            aog, bo, nullptr, nullptr, nullptr, nullptr, nullptr, nullptr);
        add_ln<0><<<4096, 256, 0, stream>>>(xg, aog, gamma, beta,
            out1 + (size_t)g * 4096 * 1024);
    }

    // ---- FFN phase: 4 row chunks of 4096 ----
    for (int c = 0; c < 4; c++) {
        const u16* o1c = out1 + (size_t)c * 4096 * 1024;
        gemm_bt<1, false><<<dim3(32, 32), 256, 0, stream>>>(o1c, W1_t, 4096, 1024,
            hid, b1, nullptr, nullptr, nullptr, nullptr, nullptr, nullptr);
        gemm_bt<0, false><<<dim3(32, 8), 256, 0, stream>>>(hid, W2_t, 1024, 4096,
            ffn, b2, nullptr, nullptr, nullptr, nullptr, nullptr, nullptr);
        add_ln<1><<<4096, 256, 0, stream>>>(o1c, ffn, gamma, beta,
            out + (size_t)c * 4096 * 1024);
    }
}